// Round 8
// baseline (881.857 us; speedup 1.0000x reference)
//
#include <hip/hip_runtime.h>

#define N_NODES 50000
#define N_EDGES 400000
#define D 512
#define NCLS 40
#define SCAN_BLOCKS ((N_NODES + 255) / 256)
#define CSTRIDE 520   // C-tile LDS stride: 1040 B = 16B-aligned, near-conflict-free

typedef __attribute__((ext_vector_type(8))) __bf16 bf16x8;
typedef __attribute__((ext_vector_type(4))) float f32x4;
typedef __attribute__((ext_vector_type(4))) float float4v;
typedef __attribute__((ext_vector_type(8))) unsigned short ushort8v;
typedef __attribute__((ext_vector_type(4))) unsigned short ushort4v;

#define AS1 __attribute__((address_space(1)))
#define AS3 __attribute__((address_space(3)))

__device__ __forceinline__ float bf2f(unsigned short u) {
  union { unsigned int i; float f; } v; v.i = ((unsigned int)u) << 16; return v.f;
}
__device__ __forceinline__ unsigned short f2bf(float f) {
  union { float f; unsigned int i; } v; v.f = f;
  unsigned int u = v.i;
  u += 0x7fffu + ((u >> 16) & 1u);  // round-nearest-even
  return (unsigned short)(u >> 16);
}

// ---------------- CSR build ----------------
__global__ void hist_kernel(const int* __restrict__ dst, int* __restrict__ counts) {
  int e = blockIdx.x * blockDim.x + threadIdx.x;
  if (e < N_EDGES) atomicAdd(&counts[dst[e]], 1);
}

__global__ __launch_bounds__(256) void scan_local_kernel(const int* __restrict__ counts,
    int* __restrict__ incl, int* __restrict__ bsum) {
  __shared__ int s[256];
  int i = blockIdx.x * 256 + threadIdx.x;
  int v = (i < N_NODES) ? counts[i] : 0;
  s[threadIdx.x] = v;
  __syncthreads();
#pragma unroll
  for (int o = 1; o < 256; o <<= 1) {
    int t = (threadIdx.x >= o) ? s[threadIdx.x - o] : 0;
    __syncthreads();
    s[threadIdx.x] += t;
    __syncthreads();
  }
  if (i < N_NODES) incl[i] = s[threadIdx.x];
  if (threadIdx.x == 255) bsum[blockIdx.x] = s[255];
}

__global__ __launch_bounds__(256) void scan_bsum_kernel(int* __restrict__ bsum) {
  __shared__ int s[256];
  int v = (threadIdx.x < SCAN_BLOCKS) ? bsum[threadIdx.x] : 0;
  s[threadIdx.x] = v;
  __syncthreads();
#pragma unroll
  for (int o = 1; o < 256; o <<= 1) {
    int t = (threadIdx.x >= o) ? s[threadIdx.x - o] : 0;
    __syncthreads();
    s[threadIdx.x] += t;
    __syncthreads();
  }
  if (threadIdx.x < SCAN_BLOCKS) bsum[threadIdx.x] = s[threadIdx.x] - v;  // exclusive
}

__global__ __launch_bounds__(256) void scan_finish_kernel(const int* __restrict__ counts,
    const int* __restrict__ bsum, int* __restrict__ row_ptr, int* __restrict__ cursor) {
  int i = blockIdx.x * 256 + threadIdx.x;
  if (i < N_NODES) {
    int inc = cursor[i] + bsum[blockIdx.x];
    row_ptr[i + 1] = inc;
    cursor[i] = inc - counts[i];
    if (i == 0) row_ptr[0] = 0;
  }
}

__global__ void fill_kernel(const int* __restrict__ src, const int* __restrict__ dst,
                            int* __restrict__ cursor, int* __restrict__ esrc) {
  int e = blockIdx.x * blockDim.x + threadIdx.x;
  if (e < N_EDGES) {
    int pos = atomicAdd(&cursor[dst[e]], 1);
    esrc[pos] = src[e];
  }
}

// ---------------- conversions ----------------
__global__ void cvt_feat_kernel(const float* __restrict__ feat, unsigned short* __restrict__ hb) {
  size_t i = (size_t)(blockIdx.x * blockDim.x + threadIdx.x) * 4;
  if (i < (size_t)N_NODES * D) {
    float4v v = *(const float4v*)&feat[i];
    ushort4v o;
    o[0] = f2bf(v[0]); o[1] = f2bf(v[1]); o[2] = f2bf(v[2]); o[3] = f2bf(v[3]);
    *(ushort4v*)&hb[i] = o;
  }
}

// All weights (W0..W2 transposed + Wc transposed-padded) in one launch.
__global__ void cvt_w_all_kernel(const float* __restrict__ W0, const float* __restrict__ W1,
                                 const float* __restrict__ W2, const float* __restrict__ Wc,
                                 unsigned short* __restrict__ Wt, unsigned short* __restrict__ Wct) {
  int i = blockIdx.x * blockDim.x + threadIdx.x;
  if (i < 3 * D * D) {
    int l = i >> 18;
    int r = i & (D * D - 1);
    int n = r >> 9, k = r & 511;
    const float* W = (l == 0) ? W0 : ((l == 1) ? W1 : W2);
    Wt[i] = f2bf(W[k * D + n]);
  } else {
    int r = i - 3 * D * D;
    if (r < 48 * D) {
      int n = r >> 9, k = r & 511;
      Wct[r] = (n < NCLS) ? f2bf(Wc[k * NCLS + n]) : (unsigned short)0;
    }
  }
}

// ---------------- aggregation: z = h + sum_{e: dst=i} h[src[e]] ----------------
// One wave per node (max TLP). At the random-1KB-gather throughput ceiling
// (~3.8 TB/s, unroll-insensitive — rounds 4/5/7).
__global__ __launch_bounds__(256) void agg_kernel(const unsigned short* __restrict__ hb,
    const int* __restrict__ row_ptr, const int* __restrict__ esrc,
    unsigned short* __restrict__ zb) {
  int w = threadIdx.x >> 6, lane = threadIdx.x & 63;
  int node = blockIdx.x * 4 + w;
  int col = lane * 8;
  const unsigned short* hcol = hb + col;
  float acc[8];
  ushort8v v = *(const ushort8v*)&hcol[(size_t)node * D];
#pragma unroll
  for (int t = 0; t < 8; ++t) acc[t] = bf2f(v[t]);
  int s = row_ptr[node], e = row_ptr[node + 1];
  int j = s;
  for (; j + 4 <= e; j += 4) {
    int i0 = esrc[j + 0], i1 = esrc[j + 1], i2 = esrc[j + 2], i3 = esrc[j + 3];
    ushort8v v0 = *(const ushort8v*)&hcol[(size_t)i0 * D];
    ushort8v v1 = *(const ushort8v*)&hcol[(size_t)i1 * D];
    ushort8v v2 = *(const ushort8v*)&hcol[(size_t)i2 * D];
    ushort8v v3 = *(const ushort8v*)&hcol[(size_t)i3 * D];
#pragma unroll
    for (int t = 0; t < 8; ++t) acc[t] += bf2f(v0[t]);
#pragma unroll
    for (int t = 0; t < 8; ++t) acc[t] += bf2f(v1[t]);
#pragma unroll
    for (int t = 0; t < 8; ++t) acc[t] += bf2f(v2[t]);
#pragma unroll
    for (int t = 0; t < 8; ++t) acc[t] += bf2f(v3[t]);
  }
  for (; j < e; ++j) {
    int sn = esrc[j];
    ushort8v nv = *(const ushort8v*)&hcol[(size_t)sn * D];
#pragma unroll
    for (int t = 0; t < 8; ++t) acc[t] += bf2f(nv[t]);
  }
  ushort8v o;
#pragma unroll
  for (int t = 0; t < 8; ++t) o[t] = f2bf(acc[t]);
  *(ushort8v*)&zb[(size_t)node * D + col] = o;
}

// ---------------- GEMM: Hout = relu(Z @ W + b), barrier-free K-loop ----------------
// One block = 64 rows x full N=512. A-tile (64 KB) staged to LDS ONCE with XOR-swizzled
// 16B chunks (slot s of row r holds chunk s^(r&7) -> conflict-free a-frag reads);
// b-frags read directly from the L2-resident 0.5 MB Wt (16 rows x 64 B full segments
// per instruction). Wave w owns n in [w*128, w*128+128): acc = 4m x 8n frags.
// Only 2 barriers total (after staging, before epilogue) vs 16 in the m97 structure.
// Epilogue stages C through LDS (stride 520) for full-line coalesced stores.
__global__ __launch_bounds__(256) void gemm_kernel(
    const unsigned short* __restrict__ Z, const unsigned short* __restrict__ Wt,
    const float* __restrict__ bias, unsigned short* __restrict__ Hout, int M) {
  __shared__ unsigned short smem[64 * CSTRIDE];  // 66.5 KB: As (64x512 swizzled) then Cs
  unsigned short* As = smem;
  const int m0 = blockIdx.x * 64;
  const int tid = threadIdx.x;
  const int lane = tid & 63;
  const int w = tid >> 6;
  const int quad = lane >> 4, r16 = lane & 15;
  const int wn = w * 128;

  // ---- stage A: each wave 16 rows, one 1KB row per instruction, swizzled on the
  // global-source side (LDS dest must stay lane-linear).
#pragma unroll
  for (int i = 0; i < 16; ++i) {
    int row = w * 16 + i;
    int gm = m0 + row; if (gm > M - 1) gm = M - 1;  // clamp; masked at store
    int gchunk = lane ^ (row & 7);
    __builtin_amdgcn_global_load_lds(
        (AS1 void*)(void*)(Z + (size_t)gm * D + gchunk * 8),
        (AS3 void*)(As + row * 512), 16, 0, 0);
  }
  __syncthreads();

  f32x4 acc[4][8];
#pragma unroll
  for (int i = 0; i < 4; ++i)
#pragma unroll
    for (int j = 0; j < 8; ++j) acc[i][j] = (f32x4){0.f, 0.f, 0.f, 0.f};

#pragma unroll 4
  for (int kt = 0; kt < 16; ++kt) {
    bf16x8 a[4];
#pragma unroll
    for (int i = 0; i < 4; ++i) {
      int row = i * 16 + r16;
      int slot = (kt * 4 + quad) ^ (row & 7);
      a[i] = *(const bf16x8*)&As[row * 512 + slot * 8];
    }
#pragma unroll
    for (int j = 0; j < 8; ++j) {
      bf16x8 b = *(const bf16x8*)&Wt[(size_t)(wn + j * 16 + r16) * D + kt * 32 + quad * 8];
#pragma unroll
      for (int i = 0; i < 4; ++i)
        acc[i][j] = __builtin_amdgcn_mfma_f32_16x16x32_bf16(a[i], b, acc[i][j], 0, 0, 0);
    }
  }

  // ---- epilogue: bias+relu -> Cs (reuse smem, stride 520) -> coalesced stores
  __syncthreads();
  unsigned short* Cs = smem;
#pragma unroll
  for (int j = 0; j < 8; ++j) {
    float bv = bias[wn + j * 16 + r16];
#pragma unroll
    for (int i = 0; i < 4; ++i) {
#pragma unroll
      for (int r = 0; r < 4; ++r) {
        int m = i * 16 + quad * 4 + r;
        float vv = acc[i][j][r] + bv;
        vv = vv > 0.f ? vv : 0.f;
        Cs[m * CSTRIDE + wn + j * 16 + r16] = f2bf(vv);
      }
    }
  }
  __syncthreads();
  // copy-out: wave w rows [w*16, w*16+16); per instr 4 rows x 128 B contiguous
#pragma unroll
  for (int it = 0; it < 4; ++it) {
    int row = w * 16 + it * 4 + (lane >> 4);
    int gm = m0 + row;
#pragma unroll
    for (int cc = 0; cc < 4; ++cc) {
      int colofs = cc * 128 + (lane & 15) * 8;
      if (gm < M) {
        ushort8v vv = *(const ushort8v*)&Cs[row * CSTRIDE + colofs];
        *(ushort8v*)&Hout[(size_t)gm * D + colofs] = vv;
      }
    }
  }
}

// ---------------- classifier: out = h3 @ Wc + bc  (bf16 MFMA, no LDS) ----------------
__global__ __launch_bounds__(256) void cls_kernel(const unsigned short* __restrict__ hb,
    const unsigned short* __restrict__ Wct, const float* __restrict__ bc,
    float* __restrict__ out) {
  int w = threadIdx.x >> 6, lane = threadIdx.x & 63;
  int quad = lane >> 4, r16 = lane & 15;
  int nb = blockIdx.x * 64 + w * 16;
  int arow = nb + r16; if (arow > N_NODES - 1) arow = N_NODES - 1;
  f32x4 acc[3];
#pragma unroll
  for (int j = 0; j < 3; ++j) acc[j] = (f32x4){0.f, 0.f, 0.f, 0.f};
#pragma unroll 4
  for (int kt = 0; kt < 16; ++kt) {
    int kk = kt * 32 + quad * 8;
    bf16x8 a = *(const bf16x8*)&hb[(size_t)arow * D + kk];
#pragma unroll
    for (int j = 0; j < 3; ++j) {
      bf16x8 b = *(const bf16x8*)&Wct[(size_t)(j * 16 + r16) * D + kk];
      acc[j] = __builtin_amdgcn_mfma_f32_16x16x32_bf16(a, b, acc[j], 0, 0, 0);
    }
  }
#pragma unroll
  for (int j = 0; j < 3; ++j) {
    int gn = j * 16 + r16;
    if (gn < NCLS) {
      float bv = bc[gn];
#pragma unroll
      for (int r = 0; r < 4; ++r) {
        int gm = nb + quad * 4 + r;
        if (gm < N_NODES) out[(size_t)gm * NCLS + gn] = acc[j][r] + bv;
      }
    }
  }
}

extern "C" void kernel_launch(void* const* d_in, const int* in_sizes, int n_in,
                              void* d_out, int out_size, void* d_ws, size_t ws_size,
                              hipStream_t stream) {
  const float* feat = (const float*)d_in[0];
  const int* src = (const int*)d_in[1];
  const int* dst = (const int*)d_in[2];
  const float* W0 = (const float*)d_in[3];
  const float* b0 = (const float*)d_in[4];
  const float* W1 = (const float*)d_in[5];
  const float* b1 = (const float*)d_in[6];
  const float* W2 = (const float*)d_in[7];
  const float* b2 = (const float*)d_in[8];
  const float* Wc = (const float*)d_in[9];
  const float* bc = (const float*)d_in[10];
  float* out = (float*)d_out;

  char* ws = (char*)d_ws;
  size_t off = 0;
  auto alloc = [&](size_t bytes) {
    char* p = ws + off;
    off += (bytes + 255) & ~(size_t)255;
    return p;
  };
  unsigned short* hb = (unsigned short*)alloc((size_t)N_NODES * D * 2);   // 51.2 MB
  unsigned short* zb = (unsigned short*)alloc((size_t)N_NODES * D * 2);   // 51.2 MB
  unsigned short* Wt = (unsigned short*)alloc((size_t)3 * D * D * 2);     // 1.5 MB
  unsigned short* Wct = (unsigned short*)alloc((size_t)48 * D * 2);       // 49 KB
  int* row_ptr = (int*)alloc((size_t)(N_NODES + 1) * 4);
  int* counts  = (int*)alloc((size_t)N_NODES * 4);
  int* cursor  = (int*)alloc((size_t)N_NODES * 4);
  int* esrc    = (int*)alloc((size_t)N_EDGES * 4);
  int* bsum    = (int*)alloc((size_t)256 * 4);

  // CSR build
  hipMemsetAsync(counts, 0, (size_t)N_NODES * 4, stream);
  hist_kernel<<<(N_EDGES + 255) / 256, 256, 0, stream>>>(dst, counts);
  scan_local_kernel<<<SCAN_BLOCKS, 256, 0, stream>>>(counts, cursor, bsum);
  scan_bsum_kernel<<<1, 256, 0, stream>>>(bsum);
  scan_finish_kernel<<<SCAN_BLOCKS, 256, 0, stream>>>(counts, bsum, row_ptr, cursor);
  fill_kernel<<<(N_EDGES + 255) / 256, 256, 0, stream>>>(src, dst, cursor, esrc);

  cvt_feat_kernel<<<(N_NODES * D / 4 + 255) / 256, 256, 0, stream>>>(feat, hb);
  cvt_w_all_kernel<<<(3 * D * D + 48 * D + 255) / 256, 256, 0, stream>>>(W0, W1, W2, Wc, Wt, Wct);

  const float* bs[3] = {b0, b1, b2};
  for (int l = 0; l < 3; ++l) {
    agg_kernel<<<N_NODES / 4, 256, 0, stream>>>(hb, row_ptr, esrc, zb);
    gemm_kernel<<<(N_NODES + 63) / 64, 256, 0, stream>>>(zb, Wt + (size_t)l * D * D, bs[l], hb, N_NODES);
  }
  cls_kernel<<<(N_NODES + 63) / 64, 256, 0, stream>>>(hb, Wct, bc, out);
}

// Round 9
// 599.647 us; speedup vs baseline: 1.4706x; 1.4706x over previous
//
#include <hip/hip_runtime.h>

#define N_NODES 50000
#define N_EDGES 400000
#define D 512
#define NCLS 40
#define SCAN_BLOCKS ((N_NODES + 255) / 256)
#define CSTRIDE 260   // C-tile LDS stride (elems): 520 B, 16B-aligned

typedef __attribute__((ext_vector_type(8))) __bf16 bf16x8;
typedef __attribute__((ext_vector_type(4))) float f32x4;
typedef __attribute__((ext_vector_type(4))) float float4v;
typedef __attribute__((ext_vector_type(8))) unsigned short ushort8v;
typedef __attribute__((ext_vector_type(4))) unsigned short ushort4v;

#define AS1 __attribute__((address_space(1)))
#define AS3 __attribute__((address_space(3)))

__device__ __forceinline__ float bf2f(unsigned short u) {
  union { unsigned int i; float f; } v; v.i = ((unsigned int)u) << 16; return v.f;
}
__device__ __forceinline__ unsigned short f2bf(float f) {
  union { float f; unsigned int i; } v; v.f = f;
  unsigned int u = v.i;
  u += 0x7fffu + ((u >> 16) & 1u);  // round-nearest-even
  return (unsigned short)(u >> 16);
}

// ---------------- CSR build ----------------
__global__ void hist_kernel(const int* __restrict__ dst, int* __restrict__ counts) {
  int e = blockIdx.x * blockDim.x + threadIdx.x;
  if (e < N_EDGES) atomicAdd(&counts[dst[e]], 1);
}

__global__ __launch_bounds__(256) void scan_local_kernel(const int* __restrict__ counts,
    int* __restrict__ incl, int* __restrict__ bsum) {
  __shared__ int s[256];
  int i = blockIdx.x * 256 + threadIdx.x;
  int v = (i < N_NODES) ? counts[i] : 0;
  s[threadIdx.x] = v;
  __syncthreads();
#pragma unroll
  for (int o = 1; o < 256; o <<= 1) {
    int t = (threadIdx.x >= o) ? s[threadIdx.x - o] : 0;
    __syncthreads();
    s[threadIdx.x] += t;
    __syncthreads();
  }
  if (i < N_NODES) incl[i] = s[threadIdx.x];
  if (threadIdx.x == 255) bsum[blockIdx.x] = s[255];
}

__global__ __launch_bounds__(256) void scan_bsum_kernel(int* __restrict__ bsum) {
  __shared__ int s[256];
  int v = (threadIdx.x < SCAN_BLOCKS) ? bsum[threadIdx.x] : 0;
  s[threadIdx.x] = v;
  __syncthreads();
#pragma unroll
  for (int o = 1; o < 256; o <<= 1) {
    int t = (threadIdx.x >= o) ? s[threadIdx.x - o] : 0;
    __syncthreads();
    s[threadIdx.x] += t;
    __syncthreads();
  }
  if (threadIdx.x < SCAN_BLOCKS) bsum[threadIdx.x] = s[threadIdx.x] - v;  // exclusive
}

__global__ __launch_bounds__(256) void scan_finish_kernel(const int* __restrict__ counts,
    const int* __restrict__ bsum, int* __restrict__ row_ptr, int* __restrict__ cursor) {
  int i = blockIdx.x * 256 + threadIdx.x;
  if (i < N_NODES) {
    int inc = cursor[i] + bsum[blockIdx.x];
    row_ptr[i + 1] = inc;
    cursor[i] = inc - counts[i];
    if (i == 0) row_ptr[0] = 0;
  }
}

__global__ void fill_kernel(const int* __restrict__ src, const int* __restrict__ dst,
                            int* __restrict__ cursor, int* __restrict__ esrc) {
  int e = blockIdx.x * blockDim.x + threadIdx.x;
  if (e < N_EDGES) {
    int pos = atomicAdd(&cursor[dst[e]], 1);
    esrc[pos] = src[e];
  }
}

// ---------------- conversions ----------------
__global__ void cvt_feat_kernel(const float* __restrict__ feat, unsigned short* __restrict__ hb) {
  size_t i = (size_t)(blockIdx.x * blockDim.x + threadIdx.x) * 4;
  if (i < (size_t)N_NODES * D) {
    float4v v = *(const float4v*)&feat[i];
    ushort4v o;
    o[0] = f2bf(v[0]); o[1] = f2bf(v[1]); o[2] = f2bf(v[2]); o[3] = f2bf(v[3]);
    *(ushort4v*)&hb[i] = o;
  }
}

// All weights (W0..W2 transposed + Wc transposed-padded) in one launch.
__global__ void cvt_w_all_kernel(const float* __restrict__ W0, const float* __restrict__ W1,
                                 const float* __restrict__ W2, const float* __restrict__ Wc,
                                 unsigned short* __restrict__ Wt, unsigned short* __restrict__ Wct) {
  int i = blockIdx.x * blockDim.x + threadIdx.x;
  if (i < 3 * D * D) {
    int l = i >> 18;
    int r = i & (D * D - 1);
    int n = r >> 9, k = r & 511;
    const float* W = (l == 0) ? W0 : ((l == 1) ? W1 : W2);
    Wt[i] = f2bf(W[k * D + n]);
  } else {
    int r = i - 3 * D * D;
    if (r < 48 * D) {
      int n = r >> 9, k = r & 511;
      Wct[r] = (n < NCLS) ? f2bf(Wc[k * NCLS + n]) : (unsigned short)0;
    }
  }
}

// ---------------- aggregation: z = h + sum_{e: dst=i} h[src[e]] ----------------
// One wave per node (max TLP). At the random-1KB-gather throughput ceiling
// (~3.8 TB/s HBM / 6.4 TB/s logical — rounds 4/5/7, unroll-insensitive).
__global__ __launch_bounds__(256) void agg_kernel(const unsigned short* __restrict__ hb,
    const int* __restrict__ row_ptr, const int* __restrict__ esrc,
    unsigned short* __restrict__ zb) {
  int w = threadIdx.x >> 6, lane = threadIdx.x & 63;
  int node = blockIdx.x * 4 + w;
  int col = lane * 8;
  const unsigned short* hcol = hb + col;
  float acc[8];
  ushort8v v = *(const ushort8v*)&hcol[(size_t)node * D];
#pragma unroll
  for (int t = 0; t < 8; ++t) acc[t] = bf2f(v[t]);
  int s = row_ptr[node], e = row_ptr[node + 1];
  int j = s;
  for (; j + 4 <= e; j += 4) {
    int i0 = esrc[j + 0], i1 = esrc[j + 1], i2 = esrc[j + 2], i3 = esrc[j + 3];
    ushort8v v0 = *(const ushort8v*)&hcol[(size_t)i0 * D];
    ushort8v v1 = *(const ushort8v*)&hcol[(size_t)i1 * D];
    ushort8v v2 = *(const ushort8v*)&hcol[(size_t)i2 * D];
    ushort8v v3 = *(const ushort8v*)&hcol[(size_t)i3 * D];
#pragma unroll
    for (int t = 0; t < 8; ++t) acc[t] += bf2f(v0[t]);
#pragma unroll
    for (int t = 0; t < 8; ++t) acc[t] += bf2f(v1[t]);
#pragma unroll
    for (int t = 0; t < 8; ++t) acc[t] += bf2f(v2[t]);
#pragma unroll
    for (int t = 0; t < 8; ++t) acc[t] += bf2f(v3[t]);
  }
  for (; j < e; ++j) {
    int sn = esrc[j];
    ushort8v nv = *(const ushort8v*)&hcol[(size_t)sn * D];
#pragma unroll
    for (int t = 0; t < 8; ++t) acc[t] += bf2f(nv[t]);
  }
  ushort8v o;
#pragma unroll
  for (int t = 0; t < 8; ++t) o[t] = f2bf(acc[t]);
  *(ushort8v*)&zb[(size_t)node * D + col] = o;
}

// ---------------- GEMM: Hout = relu(Z @ W + b), bf16 MFMA ----------------
// BM=128 x BN=256 tile, BK=32, 512 threads = 8 waves (2m x 4n of 64x64).
// Staged bytes = A 102 MB + B 195 MB = 297 MB (vs 404 MB at 128x128): the kernel
// is staging-BW bound (~7 TB/s measured), so time ~ staged bytes.
// __launch_bounds__(512,4) pins VGPR<=128 -> 2 blocks/CU resident (round-8 lesson:
// never drop below ~16 waves/CU). Epilogue stages C in LDS for full-line stores.
__global__ __launch_bounds__(512, 4) void gemm_kernel(
    const unsigned short* __restrict__ Z, const unsigned short* __restrict__ Wt,
    const float* __restrict__ bias, unsigned short* __restrict__ Hout, int M) {
  __shared__ unsigned short smem[128 * CSTRIDE];  // 66.6 KB union: As+Bs | Cs
  unsigned short* As = smem;            // [128][32] = 4096 elems
  unsigned short* Bs = smem + 4096;     // [256][32] = 8192 elems
  const int n0 = blockIdx.x * 256;      // n fastest: 2 n-tiles of one m-tile adjacent
  const int m0 = blockIdx.y * 128;
  const int tid = threadIdx.x;
  const int lane = tid & 63;
  const int w = tid >> 6;               // 0..7
  const int wm = (w >> 2) * 64;         // {0,64}
  const int wn = (w & 3) * 64;          // {0,64,128,192}
  const int quad = lane >> 4;
  const int r16 = lane & 15;

  f32x4 acc[4][4];
#pragma unroll
  for (int i = 0; i < 4; ++i)
#pragma unroll
    for (int j = 0; j < 4; ++j)
      acc[i][j] = (f32x4){0.f, 0.f, 0.f, 0.f};

  const int srow = lane >> 2;        // staging row within 16-row chunk
  const int skk = (lane & 3) * 8;    // staging k offset
  for (int kt = 0; kt < 16; ++kt) {
    __syncthreads();
    const int kbase = kt * 32 + skk;
    {
      // A: wave w stages rows [w*16, w*16+16)
      int mrow = w * 16 + srow;
      int gm = m0 + mrow; if (gm > M - 1) gm = M - 1;  // clamp; masked at store
      __builtin_amdgcn_global_load_lds(
          (AS1 void*)(void*)(Z + (size_t)gm * D + kbase),
          (AS3 void*)(As + w * 512), 16, 0, 0);
      // B: wave w stages rows [w*32, w*32+32) (2 chunks)
#pragma unroll
      for (int c = 0; c < 2; ++c) {
        int nrow = n0 + w * 32 + c * 16 + srow;
        __builtin_amdgcn_global_load_lds(
            (AS1 void*)(void*)(Wt + (size_t)nrow * D + kbase),
            (AS3 void*)(Bs + (w * 2 + c) * 512), 16, 0, 0);
      }
    }
    __syncthreads();  // drains vmcnt before use

    bf16x8 a[4];
#pragma unroll
    for (int i = 0; i < 4; ++i)
      a[i] = *(const bf16x8*)&As[(wm + i * 16 + r16) * 32 + quad * 8];
#pragma unroll
    for (int j = 0; j < 4; ++j) {
      bf16x8 b = *(const bf16x8*)&Bs[(wn + j * 16 + r16) * 32 + quad * 8];
#pragma unroll
      for (int i = 0; i < 4; ++i)
        acc[i][j] = __builtin_amdgcn_mfma_f32_16x16x32_bf16(a[i], b, acc[i][j], 0, 0, 0);
    }
  }

  // ---- epilogue: bias+relu -> Cs (128 x 256, stride 260) -> coalesced stores
  __syncthreads();  // all frag reads done before overwriting smem
  unsigned short* Cs = smem;
#pragma unroll
  for (int j = 0; j < 4; ++j) {
    float bv = bias[n0 + wn + j * 16 + r16];
#pragma unroll
    for (int i = 0; i < 4; ++i) {
      int crow = wm + i * 16 + quad * 4;
      int ccol = wn + j * 16 + r16;
#pragma unroll
      for (int r = 0; r < 4; ++r) {
        float vv = acc[i][j][r] + bv;
        vv = vv > 0.f ? vv : 0.f;
        Cs[(crow + r) * CSTRIDE + ccol] = f2bf(vv);
      }
    }
  }
  __syncthreads();
  // copy-out: per instr 512 threads x 16B: 32 lanes cover one 512B row-half; rows
  // it*16 + tid/32 cover 0..127 over 8 iters. Full 64B lines -> no write amp.
#pragma unroll
  for (int it = 0; it < 8; ++it) {
    int row = it * 16 + (tid >> 5);
    int colofs = (tid & 31) * 8;
    int gm = m0 + row;
    if (gm < M) {
      ushort8v vv = *(const ushort8v*)&Cs[row * CSTRIDE + colofs];
      *(ushort8v*)&Hout[(size_t)gm * D + n0 + colofs] = vv;
    }
  }
}

// ---------------- classifier: out = h3 @ Wc + bc  (bf16 MFMA, no LDS) ----------------
__global__ __launch_bounds__(256) void cls_kernel(const unsigned short* __restrict__ hb,
    const unsigned short* __restrict__ Wct, const float* __restrict__ bc,
    float* __restrict__ out) {
  int w = threadIdx.x >> 6, lane = threadIdx.x & 63;
  int quad = lane >> 4, r16 = lane & 15;
  int nb = blockIdx.x * 64 + w * 16;
  int arow = nb + r16; if (arow > N_NODES - 1) arow = N_NODES - 1;
  f32x4 acc[3];
#pragma unroll
  for (int j = 0; j < 3; ++j) acc[j] = (f32x4){0.f, 0.f, 0.f, 0.f};
#pragma unroll 4
  for (int kt = 0; kt < 16; ++kt) {
    int kk = kt * 32 + quad * 8;
    bf16x8 a = *(const bf16x8*)&hb[(size_t)arow * D + kk];
#pragma unroll
    for (int j = 0; j < 3; ++j) {
      bf16x8 b = *(const bf16x8*)&Wct[(size_t)(j * 16 + r16) * D + kk];
      acc[j] = __builtin_amdgcn_mfma_f32_16x16x32_bf16(a, b, acc[j], 0, 0, 0);
    }
  }
#pragma unroll
  for (int j = 0; j < 3; ++j) {
    int gn = j * 16 + r16;
    if (gn < NCLS) {
      float bv = bc[gn];
#pragma unroll
      for (int r = 0; r < 4; ++r) {
        int gm = nb + quad * 4 + r;
        if (gm < N_NODES) out[(size_t)gm * NCLS + gn] = acc[j][r] + bv;
      }
    }
  }
}

extern "C" void kernel_launch(void* const* d_in, const int* in_sizes, int n_in,
                              void* d_out, int out_size, void* d_ws, size_t ws_size,
                              hipStream_t stream) {
  const float* feat = (const float*)d_in[0];
  const int* src = (const int*)d_in[1];
  const int* dst = (const int*)d_in[2];
  const float* W0 = (const float*)d_in[3];
  const float* b0 = (const float*)d_in[4];
  const float* W1 = (const float*)d_in[5];
  const float* b1 = (const float*)d_in[6];
  const float* W2 = (const float*)d_in[7];
  const float* b2 = (const float*)d_in[8];
  const float* Wc = (const float*)d_in[9];
  const float* bc = (const float*)d_in[10];
  float* out = (float*)d_out;

  char* ws = (char*)d_ws;
  size_t off = 0;
  auto alloc = [&](size_t bytes) {
    char* p = ws + off;
    off += (bytes + 255) & ~(size_t)255;
    return p;
  };
  unsigned short* hb = (unsigned short*)alloc((size_t)N_NODES * D * 2);   // 51.2 MB
  unsigned short* zb = (unsigned short*)alloc((size_t)N_NODES * D * 2);   // 51.2 MB
  unsigned short* Wt = (unsigned short*)alloc((size_t)3 * D * D * 2);     // 1.5 MB
  unsigned short* Wct = (unsigned short*)alloc((size_t)48 * D * 2);       // 49 KB
  int* row_ptr = (int*)alloc((size_t)(N_NODES + 1) * 4);
  int* counts  = (int*)alloc((size_t)N_NODES * 4);
  int* cursor  = (int*)alloc((size_t)N_NODES * 4);
  int* esrc    = (int*)alloc((size_t)N_EDGES * 4);
  int* bsum    = (int*)alloc((size_t)256 * 4);

  // CSR build
  hipMemsetAsync(counts, 0, (size_t)N_NODES * 4, stream);
  hist_kernel<<<(N_EDGES + 255) / 256, 256, 0, stream>>>(dst, counts);
  scan_local_kernel<<<SCAN_BLOCKS, 256, 0, stream>>>(counts, cursor, bsum);
  scan_bsum_kernel<<<1, 256, 0, stream>>>(bsum);
  scan_finish_kernel<<<SCAN_BLOCKS, 256, 0, stream>>>(counts, bsum, row_ptr, cursor);
  fill_kernel<<<(N_EDGES + 255) / 256, 256, 0, stream>>>(src, dst, cursor, esrc);

  cvt_feat_kernel<<<(N_NODES * D / 4 + 255) / 256, 256, 0, stream>>>(feat, hb);
  cvt_w_all_kernel<<<(3 * D * D + 48 * D + 255) / 256, 256, 0, stream>>>(W0, W1, W2, Wc, Wt, Wct);

  dim3 ggrid(2, (N_NODES + 127) / 128);  // n-tiles fastest for A-tile reuse
  const float* bs[3] = {b0, b1, b2};
  for (int l = 0; l < 3; ++l) {
    agg_kernel<<<N_NODES / 4, 256, 0, stream>>>(hb, row_ptr, esrc, zb);
    gemm_kernel<<<ggrid, 512, 0, stream>>>(zb, Wt + (size_t)l * D * D, bs[l], hb, N_NODES);
  }
  cls_kernel<<<(N_NODES + 63) / 64, 256, 0, stream>>>(hb, Wct, bc, out);
}